// Round 6
// baseline (93.721 us; speedup 1.0000x reference)
//
#include <hip/hip_runtime.h>
#include <stdint.h>

// SortNode2Pin: per-node argmin over CSR pin slices by sorted_pin_map key.
// v6: two-phase block-staging.
//  build:  4-bit coarse-key table (4 MB, L2-resident) from key[] (NT stream).
//  main:   phase 1 — block cooperatively loads its contiguous slot range
//          (aligned int4 NT loads of n2p, 4 independent key4 gathers/thread),
//          writes packed (nib<<23|pin) to LDS via b128.
//          phase 2 — each thread scans its own segment in LDS (no binary
//          search, no atomics); exact key[] gathers only for tied nodes.

typedef int iv4 __attribute__((ext_vector_type(4)));

#define NPB 256    // nodes per block (= block size)
#define CAP 3072   // LDS slot capacity (block range mean ~1024, sigma ~64)

__global__ void build_key4_kernel(const int* __restrict__ key,
                                  uint32_t* __restrict__ key4,
                                  int num_pins, int shift) {
    int t = blockIdx.x * blockDim.x + threadIdx.x;
    int base = t * 8;
    if (base >= num_pins) return;
    if (base + 8 <= num_pins) {
        const iv4* kp = (const iv4*)(key + base);
        iv4 a = __builtin_nontemporal_load(kp);
        iv4 b = __builtin_nontemporal_load(kp + 1);
        uint32_t w = 0;
        w |= (((uint32_t)a.x >> shift) & 15u) << 0;
        w |= (((uint32_t)a.y >> shift) & 15u) << 4;
        w |= (((uint32_t)a.z >> shift) & 15u) << 8;
        w |= (((uint32_t)a.w >> shift) & 15u) << 12;
        w |= (((uint32_t)b.x >> shift) & 15u) << 16;
        w |= (((uint32_t)b.y >> shift) & 15u) << 20;
        w |= (((uint32_t)b.z >> shift) & 15u) << 24;
        w |= (((uint32_t)b.w >> shift) & 15u) << 28;
        __builtin_nontemporal_store(w, key4 + t);
    } else {
        uint32_t w = 0;
        for (int j = 0; base + j < num_pins; ++j) {
            uint32_t k = (uint32_t)key[base + j];
            w |= ((k >> shift) & 15u) << (4 * j);
        }
        __builtin_nontemporal_store(w, key4 + t);
    }
}

__device__ __forceinline__ uint32_t nib_of(const uint32_t* key4, uint32_t p) {
    uint32_t w = key4[p >> 3];
    return (w >> ((p & 7u) * 4u)) & 15u;
}

__global__ __launch_bounds__(256) void SortNode2Pin_stage_kernel(
        const int* __restrict__ starts,
        const int* __restrict__ n2p,
        const int* __restrict__ key,
        const uint32_t* __restrict__ key4,
        int* __restrict__ out,
        int num_nodes) {
    __shared__ int B[NPB + 1];
    __shared__ uint32_t slot[CAP + 4];   // packed (nib<<23)|pin, abs-aligned

    int t = threadIdx.x;
    int i0 = blockIdx.x * NPB;

    {
        int idx = i0 + t; if (idx > num_nodes) idx = num_nodes;
        B[t] = starts[idx];
        if (t == 0) {
            int idx2 = i0 + NPB; if (idx2 > num_nodes) idx2 = num_nodes;
            B[NPB] = starts[idx2];
        }
    }
    __syncthreads();

    int jbeg0 = B[0];
    int jend0 = B[NPB];
    int range = jend0 - jbeg0;

    if (range <= CAP) {
        // ---- phase 1: cooperative staging -------------------------------
        int jal = jbeg0 & ~3;                 // 16B-aligned base
        int nch = (jend0 - jal + 3) >> 2;     // int4 chunks covering range
        for (int c = t; c < nch; c += NPB) {
            int j0 = jal + (c << 2);
            uint32_t sv0, sv1, sv2, sv3;
            if (j0 >= jbeg0 && j0 + 4 <= jend0) {
                iv4 p4 = __builtin_nontemporal_load((const iv4*)(n2p + j0));
                uint32_t p0 = (uint32_t)p4.x, p1 = (uint32_t)p4.y;
                uint32_t p2 = (uint32_t)p4.z, p3 = (uint32_t)p4.w;
                sv0 = (nib_of(key4, p0) << 23) | p0;   // 4 independent gathers
                sv1 = (nib_of(key4, p1) << 23) | p1;
                sv2 = (nib_of(key4, p2) << 23) | p2;
                sv3 = (nib_of(key4, p3) << 23) | p3;
            } else {
                uint32_t sv[4];
                #pragma unroll
                for (int e = 0; e < 4; ++e) {
                    int j = j0 + e;
                    if (j >= jbeg0 && j < jend0) {
                        uint32_t p = (uint32_t)__builtin_nontemporal_load(n2p + j);
                        sv[e] = (nib_of(key4, p) << 23) | p;
                    } else {
                        sv[e] = 0xFFFFFFFFu;   // never read by phase 2
                    }
                }
                sv0 = sv[0]; sv1 = sv[1]; sv2 = sv[2]; sv3 = sv[3];
            }
            iv4 w4; w4.x = (int)sv0; w4.y = (int)sv1; w4.z = (int)sv2; w4.w = (int)sv3;
            *(iv4*)&slot[c << 2] = w4;         // ds_write_b128, conflict-free
        }
        __syncthreads();

        // ---- phase 2: per-thread segment scan in LDS --------------------
        int s = B[t] - jal;
        int e = B[t + 1] - jal;
        int mv = 16, cnt = 0;
        uint32_t bp = 0;
        for (int q = s; q < e; ++q) {
            uint32_t sp = slot[q];
            int nib = (int)(sp >> 23);
            if (nib < mv) { mv = nib; cnt = 1; bp = sp & 0x7FFFFFu; }
            else if (nib == mv) ++cnt;
        }
        int r = (int)bp;
        if (cnt > 1) {                         // tie: exact keys (rare)
            int bk = 0x7fffffff;
            for (int q = s; q < e; ++q) {
                uint32_t sp = slot[q];
                if ((int)(sp >> 23) == mv) {
                    int p = (int)(sp & 0x7FFFFFu);
                    int k = key[p];
                    if (k < bk) { bk = k; r = p; }
                }
            }
        }
        int node = i0 + t;
        if (node < num_nodes) __builtin_nontemporal_store(r, out + node);
    } else {
        // ---- pathological block range: per-thread lazy-tie scan ---------
        int node = i0 + t;
        if (node < num_nodes) {
            int s = B[t], e = B[t + 1];
            int mv = 16, bp = 0, bk = -1;
            for (int j = s; j < e; ++j) {
                uint32_t p = (uint32_t)n2p[j];
                int n = (int)nib_of(key4, p);
                if (n > mv) continue;
                if (n < mv) { mv = n; bp = (int)p; bk = -1; }
                else {
                    if (bk < 0) bk = key[bp];
                    int k = key[p];
                    if (k < bk) { bk = k; bp = (int)p; }
                }
            }
            __builtin_nontemporal_store(bp, out + node);
        }
    }
}

// Fallback if workspace too small or pins don't fit the 23-bit packing.
__global__ void SortNode2Pin_direct_kernel(const int* __restrict__ starts,
                                           const int* __restrict__ n2p,
                                           const int* __restrict__ key,
                                           int* __restrict__ out,
                                           int num_nodes) {
    int i = blockIdx.x * blockDim.x + threadIdx.x;
    if (i >= num_nodes) return;
    int s = starts[i];
    int e = starts[i + 1];
    int best_pin = 0;
    int best_key = 0x7fffffff;
    for (int j = s; j < e; ++j) {
        int p = n2p[j];
        int k = key[p];
        if (k < best_key) { best_key = k; best_pin = p; }
    }
    out[i] = best_pin;
}

extern "C" void kernel_launch(void* const* d_in, const int* in_sizes, int n_in,
                              void* d_out, int out_size, void* d_ws, size_t ws_size,
                              hipStream_t stream) {
    const int* starts = (const int*)d_in[0];   // [num_nodes+1]
    const int* n2p    = (const int*)d_in[1];   // [num_pins]
    const int* key    = (const int*)d_in[2];   // [num_pins]
    int num_nodes = out_size;
    int num_pins  = in_sizes[1];

    size_t key4_words = (size_t)((num_pins + 7) / 8);
    size_t need = key4_words * sizeof(uint32_t);

    int block = 256;
    if (ws_size >= need && num_pins < (1 << 23)) {
        int bits = 32 - __builtin_clz((unsigned)(num_pins - 1));  // ceil(log2)
        int shift = bits > 4 ? bits - 4 : 0;
        uint32_t* key4 = (uint32_t*)d_ws;

        int g1 = (int)((key4_words + block - 1) / block);
        build_key4_kernel<<<g1, block, 0, stream>>>(key, key4, num_pins, shift);

        int g2 = (num_nodes + NPB - 1) / NPB;
        SortNode2Pin_stage_kernel<<<g2, block, 0, stream>>>(
            starts, n2p, key, key4, (int*)d_out, num_nodes);
    } else {
        int grid = (num_nodes + block - 1) / block;
        SortNode2Pin_direct_kernel<<<grid, block, 0, stream>>>(
            starts, n2p, key, (int*)d_out, num_nodes);
    }
}

// Round 7
// 91.099 us; speedup vs baseline: 1.0288x; 1.0288x over previous
//
#include <hip/hip_runtime.h>
#include <stdint.h>

// SortNode2Pin: per-node argmin over CSR pin slices by sorted_pin_map key.
// v7: two-phase block staging, deepened pipes.
//  build:  4-bit coarse-key table (4 MB, L2-resident) from key[] (NT stream).
//  main:   NPB=512 nodes/block (256 threads). Phase 1: each thread stages 2
//          int4 chunks with all 8 key4 gathers in flight (8-deep MLP), packs
//          (nib<<23|pin) into LDS via b128. Phase 2: each thread scans its 2
//          segments from LDS with ds_read_b128 (4 slots/load, no atomics, no
//          search); exact key[] gathers only for tied nodes.

typedef int iv4 __attribute__((ext_vector_type(4)));

#define NPB 512    // nodes per block
#define NT  256    // threads per block
#define CAP 2560   // LDS slot capacity (block range ~2048, sd ~45 -> 11 sigma)

__global__ void build_key4_kernel(const int* __restrict__ key,
                                  uint32_t* __restrict__ key4,
                                  int num_pins, int shift) {
    int t = blockIdx.x * blockDim.x + threadIdx.x;
    int base = t * 8;
    if (base >= num_pins) return;
    if (base + 8 <= num_pins) {
        const iv4* kp = (const iv4*)(key + base);
        iv4 a = __builtin_nontemporal_load(kp);
        iv4 b = __builtin_nontemporal_load(kp + 1);
        uint32_t w = 0;
        w |= (((uint32_t)a.x >> shift) & 15u) << 0;
        w |= (((uint32_t)a.y >> shift) & 15u) << 4;
        w |= (((uint32_t)a.z >> shift) & 15u) << 8;
        w |= (((uint32_t)a.w >> shift) & 15u) << 12;
        w |= (((uint32_t)b.x >> shift) & 15u) << 16;
        w |= (((uint32_t)b.y >> shift) & 15u) << 20;
        w |= (((uint32_t)b.z >> shift) & 15u) << 24;
        w |= (((uint32_t)b.w >> shift) & 15u) << 28;
        __builtin_nontemporal_store(w, key4 + t);
    } else {
        uint32_t w = 0;
        for (int j = 0; base + j < num_pins; ++j) {
            uint32_t k = (uint32_t)key[base + j];
            w |= ((k >> shift) & 15u) << (4 * j);
        }
        __builtin_nontemporal_store(w, key4 + t);
    }
}

__device__ __forceinline__ uint32_t nib_of(const uint32_t* key4, uint32_t p) {
    uint32_t w = key4[p >> 3];
    return (w >> ((p & 7u) * 4u)) & 15u;
}

// load chunk c's 4 pins (tail-masked), c in int4 units over [jal, ...)
__device__ __forceinline__ iv4 load_chunk(const int* __restrict__ n2p,
                                          int jal, int jbeg, int jend, int c) {
    int j0 = jal + (c << 2);
    if (j0 >= jbeg && j0 + 4 <= jend) {
        return __builtin_nontemporal_load((const iv4*)(n2p + j0));
    }
    iv4 r;
    #pragma unroll
    for (int e = 0; e < 4; ++e) {
        int j = j0 + e;
        r[e] = (j >= jbeg && j < jend) ? __builtin_nontemporal_load(n2p + j)
                                       : -1;   // sentinel -> packs to 0xFFFFFFFF
    }
    return r;
}

__device__ __forceinline__ uint32_t pack_sv(const uint32_t* key4, int pi) {
    if (pi < 0) return 0xFFFFFFFFu;            // pad: nib field = 511, never min
    uint32_t p = (uint32_t)pi;
    return (nib_of(key4, p) << 23) | p;
}

__device__ __forceinline__ int scan_seg(const uint32_t* slot, int s, int e,
                                        const int* __restrict__ key) {
    int mv = 1 << 30;
    int cnt = 0;
    uint32_t bp = 0;
    for (int q = (s & ~3); q < e; q += 4) {
        iv4 v = *(const iv4*)(slot + q);       // ds_read_b128
        #pragma unroll
        for (int u = 0; u < 4; ++u) {
            int j = q + u;
            uint32_t sp = (uint32_t)v[u];
            int nib = (int)(sp >> 23);
            if (j >= s && j < e) {
                if (nib < mv) { mv = nib; cnt = 1; bp = sp & 0x7FFFFFu; }
                else if (nib == mv) ++cnt;
            }
        }
    }
    int r = (int)bp;
    if (cnt > 1) {                             // tie: exact keys (rare)
        int bk = 0x7fffffff;
        for (int q = s; q < e; ++q) {
            uint32_t sp = slot[q];
            if ((int)(sp >> 23) == mv) {
                int p = (int)(sp & 0x7FFFFFu);
                int k = key[p];
                if (k < bk) { bk = k; r = p; }
            }
        }
    }
    return r;
}

__global__ __launch_bounds__(NT) void SortNode2Pin_stage_kernel(
        const int* __restrict__ starts,
        const int* __restrict__ n2p,
        const int* __restrict__ key,
        const uint32_t* __restrict__ key4,
        int* __restrict__ out,
        int num_nodes) {
    __shared__ int B[NPB + 1];
    __shared__ __align__(16) uint32_t slot[CAP + 8];

    int t = threadIdx.x;
    int i0 = blockIdx.x * NPB;

    for (int idx = t; idx <= NPB; idx += NT) {
        int g = i0 + idx; if (g > num_nodes) g = num_nodes;
        B[idx] = starts[g];
    }
    __syncthreads();

    int jbeg0 = B[0];
    int jend0 = B[NPB];
    int range = jend0 - jbeg0;

    if (range <= CAP) {
        // ---- phase 1: cooperative staging, 8 gathers in flight ----------
        int jal = jbeg0 & ~3;                  // 16B-aligned base
        int nch = (jend0 - jal + 3) >> 2;      // int4 chunks covering range
        int c = t;
        for (; c + NT < nch; c += 2 * NT) {
            int c2 = c + NT;
            iv4 pa = load_chunk(n2p, jal, jbeg0, jend0, c);
            iv4 pb = load_chunk(n2p, jal, jbeg0, jend0, c2);
            iv4 wa, wb;
            #pragma unroll
            for (int u = 0; u < 4; ++u) wa[u] = (int)pack_sv(key4, pa[u]);
            #pragma unroll
            for (int u = 0; u < 4; ++u) wb[u] = (int)pack_sv(key4, pb[u]);
            *(iv4*)&slot[c  << 2] = wa;        // ds_write_b128
            *(iv4*)&slot[c2 << 2] = wb;
        }
        for (; c < nch; c += NT) {
            iv4 pa = load_chunk(n2p, jal, jbeg0, jend0, c);
            iv4 wa;
            #pragma unroll
            for (int u = 0; u < 4; ++u) wa[u] = (int)pack_sv(key4, pa[u]);
            *(iv4*)&slot[c << 2] = wa;
        }
        __syncthreads();

        // ---- phase 2: per-thread segment scans from LDS (b128) ----------
        int ra = scan_seg(slot, B[t] - jal, B[t + 1] - jal, key);
        int rb = scan_seg(slot, B[t + NT] - jal, B[t + NT + 1] - jal, key);
        int na = i0 + t;
        int nb = i0 + t + NT;
        if (na < num_nodes) __builtin_nontemporal_store(ra, out + na);
        if (nb < num_nodes) __builtin_nontemporal_store(rb, out + nb);
    } else {
        // ---- pathological block range: per-thread lazy-tie scan ---------
        for (int idx = t; idx < NPB; idx += NT) {
            int node = i0 + idx;
            if (node >= num_nodes) break;
            int s = B[idx], e = B[idx + 1];
            int mv = 16, bp = 0, bk = -1;
            for (int j = s; j < e; ++j) {
                uint32_t p = (uint32_t)n2p[j];
                int n = (int)nib_of(key4, p);
                if (n > mv) continue;
                if (n < mv) { mv = n; bp = (int)p; bk = -1; }
                else {
                    if (bk < 0) bk = key[bp];
                    int k = key[p];
                    if (k < bk) { bk = k; bp = (int)p; }
                }
            }
            __builtin_nontemporal_store(bp, out + node);
        }
    }
}

// Fallback if workspace too small or pins don't fit the 23-bit packing.
__global__ void SortNode2Pin_direct_kernel(const int* __restrict__ starts,
                                           const int* __restrict__ n2p,
                                           const int* __restrict__ key,
                                           int* __restrict__ out,
                                           int num_nodes) {
    int i = blockIdx.x * blockDim.x + threadIdx.x;
    if (i >= num_nodes) return;
    int s = starts[i];
    int e = starts[i + 1];
    int best_pin = 0;
    int best_key = 0x7fffffff;
    for (int j = s; j < e; ++j) {
        int p = n2p[j];
        int k = key[p];
        if (k < best_key) { best_key = k; best_pin = p; }
    }
    out[i] = best_pin;
}

extern "C" void kernel_launch(void* const* d_in, const int* in_sizes, int n_in,
                              void* d_out, int out_size, void* d_ws, size_t ws_size,
                              hipStream_t stream) {
    const int* starts = (const int*)d_in[0];   // [num_nodes+1]
    const int* n2p    = (const int*)d_in[1];   // [num_pins]
    const int* key    = (const int*)d_in[2];   // [num_pins]
    int num_nodes = out_size;
    int num_pins  = in_sizes[1];

    size_t key4_words = (size_t)((num_pins + 7) / 8);
    size_t need = key4_words * sizeof(uint32_t);

    if (ws_size >= need && num_pins < (1 << 23)) {
        int bits = 32 - __builtin_clz((unsigned)(num_pins - 1));  // ceil(log2)
        int shift = bits > 4 ? bits - 4 : 0;
        uint32_t* key4 = (uint32_t*)d_ws;

        int g1 = (int)((key4_words + NT - 1) / NT);
        build_key4_kernel<<<g1, NT, 0, stream>>>(key, key4, num_pins, shift);

        int g2 = (num_nodes + NPB - 1) / NPB;
        SortNode2Pin_stage_kernel<<<g2, NT, 0, stream>>>(
            starts, n2p, key, key4, (int*)d_out, num_nodes);
    } else {
        int grid = (num_nodes + 255) / 256;
        SortNode2Pin_direct_kernel<<<grid, 256, 0, stream>>>(
            starts, n2p, key, (int*)d_out, num_nodes);
    }
}

// Round 8
// 82.881 us; speedup vs baseline: 1.1308x; 1.0992x over previous
//
#include <hip/hip_runtime.h>
#include <stdint.h>

// SortNode2Pin: per-node argmin over CSR pin slices by sorted_pin_map key.
// v8: branch-free phase 2 via 3-min tracking; tie resolution without loops.
//  build:  4-bit coarse-key table (4 MB, L2-resident) from key[] (NT stream).
//  main:   NPB=512 nodes/block (256 threads). Phase 1: stage packed
//          (nib<<23|pin) for the block's contiguous slot range into LDS
//          (int4 NT loads, 8 gathers in flight, b128 LDS writes).
//          Phase 2: per-thread branchless 3-min scan of its segments.
//          nib unique -> done (0 gathers); 2-way nib tie -> 2 parallel
//          key[] gathers; >=3-way tie (~1.6% of nodes) -> short masked loop.

typedef int iv4 __attribute__((ext_vector_type(4)));

#define NPB 512    // nodes per block
#define NT  256    // threads per block
#define CAP 2560   // LDS slot capacity (block range ~2048, sd ~90 -> +5.7 sigma)
#define PINMASK 0x7FFFFFu

__global__ void build_key4_kernel(const int* __restrict__ key,
                                  uint32_t* __restrict__ key4,
                                  int num_pins, int shift) {
    int t = blockIdx.x * blockDim.x + threadIdx.x;
    int base = t * 8;
    if (base >= num_pins) return;
    if (base + 8 <= num_pins) {
        const iv4* kp = (const iv4*)(key + base);
        iv4 a = __builtin_nontemporal_load(kp);
        iv4 b = __builtin_nontemporal_load(kp + 1);
        uint32_t w = 0;
        w |= (((uint32_t)a.x >> shift) & 15u) << 0;
        w |= (((uint32_t)a.y >> shift) & 15u) << 4;
        w |= (((uint32_t)a.z >> shift) & 15u) << 8;
        w |= (((uint32_t)a.w >> shift) & 15u) << 12;
        w |= (((uint32_t)b.x >> shift) & 15u) << 16;
        w |= (((uint32_t)b.y >> shift) & 15u) << 20;
        w |= (((uint32_t)b.z >> shift) & 15u) << 24;
        w |= (((uint32_t)b.w >> shift) & 15u) << 28;
        __builtin_nontemporal_store(w, key4 + t);
    } else {
        uint32_t w = 0;
        for (int j = 0; base + j < num_pins; ++j) {
            uint32_t k = (uint32_t)key[base + j];
            w |= ((k >> shift) & 15u) << (4 * j);
        }
        __builtin_nontemporal_store(w, key4 + t);
    }
}

__device__ __forceinline__ uint32_t nib_of(const uint32_t* key4, uint32_t p) {
    uint32_t w = key4[p >> 3];
    return (w >> ((p & 7u) * 4u)) & 15u;
}

__device__ __forceinline__ iv4 load_chunk(const int* __restrict__ n2p,
                                          int jal, int jbeg, int jend, int c) {
    int j0 = jal + (c << 2);
    if (j0 >= jbeg && j0 + 4 <= jend) {
        return __builtin_nontemporal_load((const iv4*)(n2p + j0));
    }
    iv4 r;
    #pragma unroll
    for (int e = 0; e < 4; ++e) {
        int j = j0 + e;
        r[e] = (j >= jbeg && j < jend) ? __builtin_nontemporal_load(n2p + j)
                                       : -1;   // sentinel -> packs to 0xFFFFFFFF
    }
    return r;
}

__device__ __forceinline__ uint32_t pack_sv(const uint32_t* key4, int pi) {
    if (pi < 0) return 0xFFFFFFFFu;
    uint32_t p = (uint32_t)pi;
    return (nib_of(key4, p) << 23) | p;
}

// branch-free 3-smallest insert
__device__ __forceinline__ void upd3(uint32_t sp, uint32_t& m1, uint32_t& m2,
                                     uint32_t& m3) {
    uint32_t a = min(sp, m1);
    uint32_t b = max(sp, m1);
    uint32_t c = min(b, m2);
    uint32_t d = max(b, m2);
    m1 = a; m2 = c; m3 = min(d, m3);
}

__device__ __forceinline__ int scan_seg3(const uint32_t* slot, int s, int e,
                                         const int* __restrict__ key) {
    if (e <= s) return 0;                      // empty node -> 0
    uint32_t m1 = ~0u, m2 = ~0u, m3 = ~0u;
    for (int q = (s & ~3); q < e; q += 4) {
        iv4 v = *(const iv4*)(slot + q);       // ds_read_b128
        #pragma unroll
        for (int u = 0; u < 4; ++u) {
            int j = q + u;
            uint32_t sp = (uint32_t)v[u];
            sp = (j >= s && j < e) ? sp : ~0u; // mask foreign/pad slots
            upd3(sp, m1, m2, m3);
        }
    }
    uint32_t nib1 = m1 >> 23;
    if ((m2 >> 23) != nib1) return (int)(m1 & PINMASK);    // unique min nib
    if ((m3 >> 23) != nib1) {                              // exactly 2 tied
        int p1 = (int)(m1 & PINMASK), p2 = (int)(m2 & PINMASK);
        int k1 = key[p1], k2 = key[p2];                    // 2 parallel gathers
        return k1 < k2 ? p1 : p2;
    }
    // >=3 tied at min nibble (rare): masked scan with exact keys
    int bk = 0x7fffffff, r = 0;
    for (int q = s; q < e; ++q) {
        uint32_t sp = slot[q];
        if ((sp >> 23) == nib1) {
            int p = (int)(sp & PINMASK);
            int k = key[p];
            if (k < bk) { bk = k; r = p; }
        }
    }
    return r;
}

__global__ __launch_bounds__(NT) void SortNode2Pin_stage_kernel(
        const int* __restrict__ starts,
        const int* __restrict__ n2p,
        const int* __restrict__ key,
        const uint32_t* __restrict__ key4,
        int* __restrict__ out,
        int num_nodes) {
    __shared__ __align__(16) uint32_t slot[CAP + 8];

    int t = threadIdx.x;
    int i0 = blockIdx.x * NPB;

    // block slot range (uniform -> scalar loads)
    int iend = i0 + NPB; if (iend > num_nodes) iend = num_nodes;
    int jbeg0 = starts[i0 < num_nodes ? i0 : num_nodes];
    int jend0 = starts[iend];

    // per-thread segment bounds straight from global (L1-served, coalesced)
    int iA = i0 + t;        if (iA > num_nodes) iA = num_nodes;
    int iA1 = iA + 1;       if (iA1 > num_nodes) iA1 = num_nodes;
    int iB = i0 + NT + t;   if (iB > num_nodes) iB = num_nodes;
    int iB1 = iB + 1;       if (iB1 > num_nodes) iB1 = num_nodes;
    int sA = starts[iA], eA = starts[iA1];
    int sB = starts[iB], eB = starts[iB1];

    int range = jend0 - jbeg0;

    if (range <= CAP) {
        // ---- phase 1: cooperative staging, 8 gathers in flight ----------
        int jal = jbeg0 & ~3;
        int nch = (jend0 - jal + 3) >> 2;
        int c = t;
        for (; c + NT < nch; c += 2 * NT) {
            int c2 = c + NT;
            iv4 pa = load_chunk(n2p, jal, jbeg0, jend0, c);
            iv4 pb = load_chunk(n2p, jal, jbeg0, jend0, c2);
            iv4 wa, wb;
            #pragma unroll
            for (int u = 0; u < 4; ++u) wa[u] = (int)pack_sv(key4, pa[u]);
            #pragma unroll
            for (int u = 0; u < 4; ++u) wb[u] = (int)pack_sv(key4, pb[u]);
            *(iv4*)&slot[c  << 2] = wa;
            *(iv4*)&slot[c2 << 2] = wb;
        }
        for (; c < nch; c += NT) {
            iv4 pa = load_chunk(n2p, jal, jbeg0, jend0, c);
            iv4 wa;
            #pragma unroll
            for (int u = 0; u < 4; ++u) wa[u] = (int)pack_sv(key4, pa[u]);
            *(iv4*)&slot[c << 2] = wa;
        }
        __syncthreads();

        // ---- phase 2: branchless 3-min scans ----------------------------
        int ra = scan_seg3(slot, sA - jal, eA - jal, key);
        int rb = scan_seg3(slot, sB - jal, eB - jal, key);
        int na = i0 + t;
        int nb = i0 + NT + t;
        if (na < num_nodes) __builtin_nontemporal_store(ra, out + na);
        if (nb < num_nodes) __builtin_nontemporal_store(rb, out + nb);
    } else {
        // ---- pathological block range: per-thread lazy-tie scan ---------
        for (int idx = t; idx < NPB; idx += NT) {
            int node = i0 + idx;
            if (node >= num_nodes) break;
            int s = starts[node], e = starts[node + 1];
            int mv = 16, bp = 0, bk = -1;
            for (int j = s; j < e; ++j) {
                uint32_t p = (uint32_t)n2p[j];
                int n = (int)nib_of(key4, p);
                if (n > mv) continue;
                if (n < mv) { mv = n; bp = (int)p; bk = -1; }
                else {
                    if (bk < 0) bk = key[bp];
                    int k = key[p];
                    if (k < bk) { bk = k; bp = (int)p; }
                }
            }
            __builtin_nontemporal_store(bp, out + node);
        }
    }
}

// Fallback if workspace too small or pins don't fit the 23-bit packing.
__global__ void SortNode2Pin_direct_kernel(const int* __restrict__ starts,
                                           const int* __restrict__ n2p,
                                           const int* __restrict__ key,
                                           int* __restrict__ out,
                                           int num_nodes) {
    int i = blockIdx.x * blockDim.x + threadIdx.x;
    if (i >= num_nodes) return;
    int s = starts[i];
    int e = starts[i + 1];
    int best_pin = 0;
    int best_key = 0x7fffffff;
    for (int j = s; j < e; ++j) {
        int p = n2p[j];
        int k = key[p];
        if (k < best_key) { best_key = k; best_pin = p; }
    }
    out[i] = best_pin;
}

extern "C" void kernel_launch(void* const* d_in, const int* in_sizes, int n_in,
                              void* d_out, int out_size, void* d_ws, size_t ws_size,
                              hipStream_t stream) {
    const int* starts = (const int*)d_in[0];   // [num_nodes+1]
    const int* n2p    = (const int*)d_in[1];   // [num_pins]
    const int* key    = (const int*)d_in[2];   // [num_pins]
    int num_nodes = out_size;
    int num_pins  = in_sizes[1];

    size_t key4_words = (size_t)((num_pins + 7) / 8);
    size_t need = key4_words * sizeof(uint32_t);

    if (ws_size >= need && num_pins < (1 << 23)) {
        int bits = 32 - __builtin_clz((unsigned)(num_pins - 1));  // ceil(log2)
        int shift = bits > 4 ? bits - 4 : 0;
        uint32_t* key4 = (uint32_t*)d_ws;

        int g1 = (int)((key4_words + NT - 1) / NT);
        build_key4_kernel<<<g1, NT, 0, stream>>>(key, key4, num_pins, shift);

        int g2 = (num_nodes + NPB - 1) / NPB;
        SortNode2Pin_stage_kernel<<<g2, NT, 0, stream>>>(
            starts, n2p, key, key4, (int*)d_out, num_nodes);
    } else {
        int grid = (num_nodes + 255) / 256;
        SortNode2Pin_direct_kernel<<<grid, 256, 0, stream>>>(
            starts, n2p, key, (int*)d_out, num_nodes);
    }
}